// Round 3
// baseline (9307.354 us; speedup 1.0000x reference)
//
#include <hip/hip_runtime.h>
#include <hip/hip_bf16.h>
#include <stdint.h>

typedef __bf16 bf16_t;
typedef __bf16 bf16x8 __attribute__((ext_vector_type(8)));
typedef float f32x4 __attribute__((ext_vector_type(4)));
typedef unsigned long long ull;

#define LSTM_T 256
#define LSTM_O 10
#define NSL 8        // hidden slices (8 blocks cooperate per bt)
#define THREADS 512  // waves 0-3: group A (btA), waves 4-7: group B (btB)

// ws layout (~4.66 MB)
#define WS_FLAGS 0                            // 64 bt * 8 slices * 128B = 64KB, memset 0
#define WS_W2    (64 * 1024)                  // 512KB bf16 Wh
#define WS_EBUF  (WS_W2 + 512 * 1024)         // 2 * 64 * 16KB = 2MB  (bf16 h exchange [32][256])
#define WS_EXF   (WS_EBUF + 2 * 1024 * 1024)  // 64 * 32KB = 2MB      (fp32 h_T [32][256])

__device__ __forceinline__ float sigmoid_f(float x) { return 1.0f / (1.0f + __expf(-x)); }
__device__ __forceinline__ float tanh_f(float x)    { return 2.0f / (1.0f + __expf(-2.0f * x)) - 1.0f; }
// XOR swizzle on element index of a [32][256] bf16 tile (flips 16B granules)
__device__ __forceinline__ int hsw(int r, int k) { return (r * 256 + k) ^ ((r & 7) << 3); }

__device__ __forceinline__ void gbar(int* c, int tgt) {  // 4-wave sub-barrier (LDS)
    if ((threadIdx.x & 63) == 0)
        __hip_atomic_fetch_add(c, 1, __ATOMIC_ACQ_REL, __HIP_MEMORY_SCOPE_WORKGROUP);
    while (__hip_atomic_load(c, __ATOMIC_ACQUIRE, __HIP_MEMORY_SCOPE_WORKGROUP) < tgt) {}
}

__device__ __forceinline__ unsigned int pack2(float a, float b) {
    unsigned short ua = __builtin_bit_cast(unsigned short, (bf16_t)a);
    unsigned short ub = __builtin_bit_cast(unsigned short, (bf16_t)b);
    return (unsigned int)ua | ((unsigned int)ub << 16);
}

__global__ void __launch_bounds__(256) cast_wh_kernel(const float* __restrict__ Wh,
                                                      bf16_t* __restrict__ W2) {
    int idx = (blockIdx.x * 256 + threadIdx.x) * 4;
    float4 v = *(const float4*)(Wh + idx);
    bf16_t tmp[4] = {(bf16_t)v.x, (bf16_t)v.y, (bf16_t)v.z, (bf16_t)v.w};
    *(uint2*)(W2 + idx) = *(uint2*)tmp;
}

__global__ void __launch_bounds__(THREADS, 2) lstm_kernel(
    const float* __restrict__ x,     // [B, T]
    const float* __restrict__ Wx,    // [4*H]
    const float* __restrict__ bx,    // [4*H]
    const float* __restrict__ bh,    // [4*H]
    const float* __restrict__ W_ph,  // [O, H]
    const float* __restrict__ b_ph,  // [O]
    float* __restrict__ out,         // [B, O]
    char* __restrict__ ws)
{
    __shared__ __align__(16) bf16_t h_lds[2][32 * 256];   // 16KB per group, swizzled
    __shared__ __align__(16) float  x_lds[2][32 * 257];   // 32.9KB per group
    __shared__ int gbc[2];

    const bf16_t* W2 = (const bf16_t*)(ws + WS_W2);

    const int tid  = threadIdx.x;
    const int wave = tid >> 6;
    const int lane = tid & 63;
    const int gid  = wave >> 2;             // group 0/1
    const int w    = wave & 3;              // role within group
    const int m    = w & 1;                 // M-tile (16 rows)
    const int cg   = (w >> 1) & 1;          // 16-col group within 32-col slice
    const int n    = lane & 15;
    const int grp  = lane >> 4;
    const int j    = blockIdx.x >> 5;       // slice 0..7
    const int bt   = ((blockIdx.x & 31) << 1) | gid;   // 64 bt of 32 rows
    const int b0   = bt * 32;
    const int gtid = w * 64 + lane;         // 0..255 within group
    const int hcol = j * 32 + cg * 16 + n;  // global hidden column

    int* myflag  = (int*)(ws + WS_FLAGS + (size_t)(bt * NSL + j) * 128);
    int* btflags = (int*)(ws + WS_FLAGS + (size_t)bt * NSL * 128);

    if (tid < 2) gbc[tid] = 0;
    // stage x tile [32][256] fp32 (coalesced)
#pragma unroll
    for (int i = 0; i < 32; ++i) {
        int d = gtid + i * 256;
        int row = d >> 8, col = d & 255;
        x_lds[gid][row * 257 + col] = x[(size_t)(b0 + row) * 256 + col];
    }
    // zero h (2048 u64)
#pragma unroll
    for (int i = 0; i < 8; ++i) ((ull*)h_lds[gid])[gtid + i * 256] = 0ull;

    // weight slice -> VGPRs (4 gates x 8 kk x 16B = 128 VGPR), pinned vs rematerialization
    f32x4 bW[4][8];
#pragma unroll
    for (int g = 0; g < 4; ++g)
#pragma unroll
        for (int kk = 0; kk < 8; ++kk) {
            bW[g][kk] = *(const f32x4*)(W2 + (size_t)(g * 256 + hcol) * 256 + kk * 32 + grp * 8);
            asm volatile("" : "+v"(bW[g][kk]));
        }

    float wxv[4], biv[4];
#pragma unroll
    for (int g = 0; g < 4; ++g) {
        wxv[g] = Wx[g * 256 + hcol];
        biv[g] = bx[g * 256 + hcol] + bh[g * 256 + hcol];
    }

    float c_st[4] = {0.f, 0.f, 0.f, 0.f};
    float hval[4];
    int gbt = 0;
    __syncthreads();

    for (int t = 0; t < LSTM_T; ++t) {
        // A-frags from group LDS
        bf16x8 aF[8];
#pragma unroll
        for (int kk = 0; kk < 8; ++kk)
            aF[kk] = *(const bf16x8*)&h_lds[gid][hsw(m * 16 + n, kk * 32 + grp * 8)];

        f32x4 acc[4];
#pragma unroll
        for (int g = 0; g < 4; ++g) acc[g] = (f32x4){0.f, 0.f, 0.f, 0.f};
#pragma unroll
        for (int g = 0; g < 4; ++g)
#pragma unroll
            for (int kk = 0; kk < 8; ++kk)
                acc[g] = __builtin_amdgcn_mfma_f32_16x16x32_bf16(
                    aF[kk], __builtin_bit_cast(bf16x8, bW[g][kk]), acc[g], 0, 0, 0);

        // pointwise: lane owns rows r = m*16+grp*4+q, col hcol
#pragma unroll
        for (int q = 0; q < 4; ++q) {
            int r = m * 16 + grp * 4 + q;
            float xt = x_lds[gid][r * 257 + t];
            float z0 = acc[0][q] + xt * wxv[0] + biv[0];
            float z1 = acc[1][q] + xt * wxv[1] + biv[1];
            float z2 = acc[2][q] + xt * wxv[2] + biv[2];
            float z3 = acc[3][q] + xt * wxv[3] + biv[3];
            float gg = tanh_f(z0);
            float ii = sigmoid_f(z1);
            float ff = sigmoid_f(z2);
            float oo = sigmoid_f(z3);
            float cn = gg * ii + c_st[q] * ff;
            c_st[q] = cn;
            hval[q] = tanh_f(cn) * oo;
        }

        if (t < LSTM_T - 1) {
            // post own slice (bf16) to double-buffered exchange
            ull* ebuf = (ull*)(ws + WS_EBUF + (size_t)((((t + 1) & 1) << 6) | bt) * 16384);
#pragma unroll
            for (int q = 0; q < 4; ++q) {
                float nb = __shfl_xor(hval[q], 1);
                unsigned int p01 = pack2(hval[q], nb);
                unsigned int p23 = __shfl_xor(p01, 2);
                ull v64 = (ull)p01 | ((ull)p23 << 32);
                if ((lane & 3) == 0) {
                    int r = m * 16 + grp * 4 + q;
                    __hip_atomic_store(&ebuf[(r * 256 + hcol) >> 2], v64,
                                       __ATOMIC_RELAXED, __HIP_MEMORY_SCOPE_AGENT);
                }
            }
            asm volatile("s_waitcnt vmcnt(0)" ::: "memory");   // own stores visible
            gbt += 4; gbar(&gbc[gid], gbt);                    // all 4 waves posted
            if (w == 0 && lane == 0)
                __hip_atomic_store(myflag, t + 1, __ATOMIC_RELEASE, __HIP_MEMORY_SCOPE_AGENT);
            // poll 8 slice flags (padded 128B slots)
            {
                int tgt = t + 1;
                while (true) {
                    int v = tgt;
                    if (lane < 8)
                        v = __hip_atomic_load(btflags + lane * 32, __ATOMIC_ACQUIRE,
                                              __HIP_MEMORY_SCOPE_AGENT);
                    if (__all(v >= tgt)) break;
                    __builtin_amdgcn_s_sleep(1);
                }
            }
            // stage full h_{t+1} -> group LDS (swizzled)
#pragma unroll
            for (int i = 0; i < 8; ++i) {
                int d = gtid + i * 256;   // u64 index over [32][256] bf16
                ull v = __hip_atomic_load(ebuf + d, __ATOMIC_RELAXED, __HIP_MEMORY_SCOPE_AGENT);
                int row = d >> 6;
                int e   = (d & 63) << 2;
                int s   = (row * 256 + e) ^ ((row & 7) << 3);
                *(ull*)((char*)h_lds[gid] + (size_t)s * 2) = v;
            }
            gbt += 4; gbar(&gbc[gid], gbt);                    // staging complete
        } else {
            // final step: publish fp32 h_T
            float* exf = (float*)(ws + WS_EXF + (size_t)bt * 32768);
#pragma unroll
            for (int q = 0; q < 4; ++q) {
                int r = m * 16 + grp * 4 + q;
                __hip_atomic_store(&exf[r * 256 + hcol], hval[q],
                                   __ATOMIC_RELAXED, __HIP_MEMORY_SCOPE_AGENT);
            }
            asm volatile("s_waitcnt vmcnt(0)" ::: "memory");
            gbt += 4; gbar(&gbc[gid], gbt);
            if (w == 0 && lane == 0)
                __hip_atomic_store(myflag, LSTM_T, __ATOMIC_RELEASE, __HIP_MEMORY_SCOPE_AGENT);
        }
    }

    // fused projection: slice-0 blocks project their two bt
    if (j == 0) {
        {
            int tgt = LSTM_T;
            while (true) {
                int v = tgt;
                if (lane < 8)
                    v = __hip_atomic_load(btflags + lane * 32, __ATOMIC_ACQUIRE,
                                          __HIP_MEMORY_SCOPE_AGENT);
                if (__all(v >= tgt)) break;
                __builtin_amdgcn_s_sleep(1);
            }
        }
        const float* exf = (const float*)(ws + WS_EXF + (size_t)bt * 32768);
#pragma unroll
        for (int i = 0; i < 32; ++i) {
            int d = gtid + i * 256;
            int row = d >> 8, col = d & 255;
            float v = __hip_atomic_load(exf + row * 256 + col,
                                        __ATOMIC_RELAXED, __HIP_MEMORY_SCOPE_AGENT);
            x_lds[gid][row * 257 + col] = v;
        }
        gbt += 4; gbar(&gbc[gid], gbt);

        int o = gtid & 15;
        if (o < LSTM_O) {
#pragma unroll
            for (int p = 0; p < 2; ++p) {
                int row = p * 16 + (gtid >> 4);
                const float* hrow = &x_lds[gid][row * 257];
                const float* wrow = W_ph + o * 256;
                float s = 0.f;
#pragma unroll 4
                for (int k = 0; k < 256; ++k) s += hrow[k] * wrow[k];
                out[(size_t)(b0 + row) * LSTM_O + o] = s + b_ph[o];
            }
        }
    }
}

extern "C" void kernel_launch(void* const* d_in, const int* in_sizes, int n_in,
                              void* d_out, int out_size, void* d_ws, size_t ws_size,
                              hipStream_t stream) {
    const float* x    = (const float*)d_in[0];
    const float* Wx   = (const float*)d_in[1];
    const float* bx   = (const float*)d_in[2];
    const float* Wh   = (const float*)d_in[3];
    const float* bh   = (const float*)d_in[4];
    const float* W_ph = (const float*)d_in[5];
    const float* b_ph = (const float*)d_in[6];
    float* out = (float*)d_out;
    char* ws   = (char*)d_ws;

    hipMemsetAsync(ws + WS_FLAGS, 0, 64 * 1024, stream);   // zero epoch flags
    cast_wh_kernel<<<256, 256, 0, stream>>>(Wh, (bf16_t*)(ws + WS_W2));
    lstm_kernel<<<256, THREADS, 0, stream>>>(x, Wx, bx, bh, W_ph, b_ph, out, ws);
}

// Round 5
// 2249.181 us; speedup vs baseline: 4.1381x; 4.1381x over previous
//
#include <hip/hip_runtime.h>
#include <hip/hip_bf16.h>

typedef __bf16 bf16_t;
typedef __bf16 bf16x8 __attribute__((ext_vector_type(8)));
typedef float f32x4 __attribute__((ext_vector_type(4)));

#define LSTM_T 256
#define LSTM_O 10
#define BTILE 16
#define NBLK 128     // 2048 / 16
#define THREADS 1024 // 16 waves; wave w owns hidden cols [w*16, w*16+16), all 4 gates
#define XSTRIDE 260  // fp32 x-tile row stride: 16B-aligned rows, ≤2-way LDS conflicts

__device__ __forceinline__ float sigmoid_f(float x) { return 1.0f / (1.0f + __expf(-x)); }
// safe at both extremes (no NaN)
__device__ __forceinline__ float tanh_f(float x)    { return 2.0f / (1.0f + __expf(-2.0f * x)) - 1.0f; }
// XOR-swizzle on element index of an [16][256] bf16 tile: A-frag ds_read_b128 conflict-free-ish
__device__ __forceinline__ int hsw(int r, int k) { return (r * 256 + k) ^ ((r & 7) << 3); }

// combined wait+barrier, no vmcnt drain: weight prefetch loads stay in flight
#define LDS_BARRIER() asm volatile("s_waitcnt lgkmcnt(0)\n\ts_barrier" ::: "memory")

__global__ void __launch_bounds__(256) cast_wh_kernel(const float* __restrict__ Wh,
                                                      bf16_t* __restrict__ W2) {
    int idx = (blockIdx.x * 256 + threadIdx.x) * 4;
    float4 v = *(const float4*)(Wh + idx);
    bf16_t tmp[4] = {(bf16_t)v.x, (bf16_t)v.y, (bf16_t)v.z, (bf16_t)v.w};
    *(uint2*)(W2 + idx) = *(uint2*)tmp;
}

__global__ void __launch_bounds__(THREADS) lstm_kernel(
    const float* __restrict__ x,     // [B, T]
    const float* __restrict__ Wx,    // [4*H]
    const float* __restrict__ bx,    // [4*H]
    const float* __restrict__ bh,    // [4*H]
    const bf16_t* __restrict__ W2,   // [4*H][H] bf16
    const float* __restrict__ W_ph,  // [O, H]
    const float* __restrict__ b_ph,  // [O]
    float* __restrict__ out)         // [B, O]
{
    __shared__ __align__(16) bf16_t h_sh[2][16 * 256];   // double-buffered h_t (8KB each)
    __shared__ __align__(16) float  x_sh[16 * XSTRIDE];  // x tile; reused for fp32 h_T at the end

    const int tid  = threadIdx.x;
    const int wave = tid >> 6;
    const int lane = tid & 63;
    const int n    = lane & 15;   // A-frag row / output col within 16-tile
    const int grp  = lane >> 4;   // 0..3
    const int b0   = blockIdx.x * BTILE;
    const int hh   = wave * 16 + n;   // this lane's hidden column

    // ---- one-time staging ----
#pragma unroll
    for (int i = 0; i < 4; ++i) {
        int d = tid + i * 1024;           // 4096 fp32 of x tile [16][256]
        int row = d >> 8, col = d & 255;
        x_sh[row * XSTRIDE + col] = x[(size_t)(b0 + row) * 256 + col];
    }
    if (tid < 2048) ((unsigned int*)h_sh[0])[tid] = 0u;   // zero h buffer 0

    float wxv[4], biv[4];
#pragma unroll
    for (int g = 0; g < 4; ++g) {
        wxv[g] = Wx[g * 256 + hh];
        biv[g] = bx[g * 256 + hh] + bh[g * 256 + hh];
    }
    const bf16_t* wp = W2 + (size_t)hh * 256 + grp * 8;   // B-frag base (row hh, k-offset grp*8)

    float c_st[4] = {0.f, 0.f, 0.f, 0.f};
    __syncthreads();

    for (int t = 0; t < LSTM_T; ++t) {
        const bf16_t* hbuf = h_sh[t & 1];

        // A-frags: lane holds h[row n][k = kk*32 + grp*8 .. +7]
        bf16x8 aF[8];
#pragma unroll
        for (int kk = 0; kk < 8; ++kk)
            aF[kk] = *(const bf16x8*)&hbuf[hsw(n, kk * 32 + grp * 8)];

        f32x4 acc[4];
#pragma unroll
        for (int g = 0; g < 4; ++g) acc[g] = (f32x4){0.f, 0.f, 0.f, 0.f};

        // weight stream from L2: compiler schedules the 32 dwordx4 loads with
        // counted vmcnt against the MFMAs (no barrier drains them anymore)
#pragma unroll
        for (int g = 0; g < 4; ++g) {
            const bf16_t* wg = wp + (size_t)g * 65536;
#pragma unroll
            for (int kk = 0; kk < 8; ++kk) {
                bf16x8 bF = *(const bf16x8*)(wg + kk * 32);
                acc[g] = __builtin_amdgcn_mfma_f32_16x16x32_bf16(aF[kk], bF, acc[g], 0, 0, 0);
            }
        }

        // pointwise: lane owns rows r = grp*4+q, col hh
        float hval[4];
#pragma unroll
        for (int q = 0; q < 4; ++q) {
            int r = grp * 4 + q;
            float xt = x_sh[r * XSTRIDE + t];
            float z0 = acc[0][q] + xt * wxv[0] + biv[0];
            float z1 = acc[1][q] + xt * wxv[1] + biv[1];
            float z2 = acc[2][q] + xt * wxv[2] + biv[2];
            float z3 = acc[3][q] + xt * wxv[3] + biv[3];
            float gg = tanh_f(z0);
            float ii = sigmoid_f(z1);
            float ff = sigmoid_f(z2);
            float oo = sigmoid_f(z3);
            float cn = gg * ii + c_st[q] * ff;
            c_st[q] = cn;
            hval[q] = tanh_f(cn) * oo;
        }

        if (t < LSTM_T - 1) {
            bf16_t* nb = h_sh[(t + 1) & 1];
#pragma unroll
            for (int q = 0; q < 4; ++q)
                nb[hsw(grp * 4 + q, hh)] = (bf16_t)hval[q];
            LDS_BARRIER();   // writes(t) visible before reads(t+1); weight loads NOT drained
        } else {
            LDS_BARRIER();   // all x_sh reads done before overwrite
#pragma unroll
            for (int q = 0; q < 4; ++q)
                x_sh[(grp * 4 + q) * XSTRIDE + hh] = hval[q];   // fp32 h_T
            LDS_BARRIER();
        }
    }

    // fused output projection: out[b0+r][o] = h_T[r] . W_ph[o] + b_ph[o]
    if (tid < 16 * LSTM_O) {
        int r = tid & 15;
        int o = tid >> 4;
        const float* wrow = W_ph + o * 256;
        const float* hrow = x_sh + r * XSTRIDE;
        float s = 0.f;
#pragma unroll 4
        for (int k0 = 0; k0 < 256; ++k0) {
            int k = (k0 + r * 16) & 255;   // rotate start to dodge LDS bank conflicts
            s += hrow[k] * wrow[k];
        }
        out[(size_t)(b0 + r) * LSTM_O + o] = s + b_ph[o];
    }
}

extern "C" void kernel_launch(void* const* d_in, const int* in_sizes, int n_in,
                              void* d_out, int out_size, void* d_ws, size_t ws_size,
                              hipStream_t stream) {
    const float* x    = (const float*)d_in[0];
    const float* Wx   = (const float*)d_in[1];
    const float* bx   = (const float*)d_in[2];
    const float* Wh   = (const float*)d_in[3];
    const float* bh   = (const float*)d_in[4];
    const float* W_ph = (const float*)d_in[5];
    const float* b_ph = (const float*)d_in[6];
    float* out  = (float*)d_out;
    bf16_t* W2  = (bf16_t*)d_ws;   // 512 KB bf16 copy of Wh (ws re-poisoned each call; rebuilt)

    cast_wh_kernel<<<256, 256, 0, stream>>>(Wh, W2);
    lstm_kernel<<<NBLK, THREADS, 0, stream>>>(x, Wx, bx, bh, W2, W_ph, b_ph, out);
}

// Round 7
// 945.940 us; speedup vs baseline: 9.8393x; 2.3777x over previous
//
#include <hip/hip_runtime.h>
#include <hip/hip_bf16.h>

typedef int  i32x4 __attribute__((ext_vector_type(4)));
typedef unsigned long long ull;

#define LSTM_T 256
#define LSTM_O 10
#define BTILE 16
#define NBLK 128     // 2048/16 batch tiles
#define THREADS 512  // 8 waves; wave w owns hidden cols [w*32, w*32+32) as 2 16-col tiles
#define XSTRIDE 260

// ws: [0, 256KB) i8 weights W2q[4*256][256]; [256KB, +4KB) fp32 dequant dq[1024]
#define WS_WQ 0
#define WS_DQ (256 * 1024)

__device__ __forceinline__ float sigmoid_f(float x) { return 1.0f / (1.0f + __expf(-x)); }
__device__ __forceinline__ float tanh_f(float x)    { return 2.0f / (1.0f + __expf(-2.0f * x)) - 1.0f; }

// one barrier per step; only LDS traffic in the loop, so lgkmcnt is the only wait needed
#define LDS_BARRIER() asm volatile("s_waitcnt lgkmcnt(0)\n\ts_barrier" ::: "memory")

// per-(gate,out-col) symmetric i8 quantization of Wh; one wave per row
__global__ void __launch_bounds__(64) quant_wh_kernel(const float* __restrict__ Wh,
                                                      char* __restrict__ Wq,
                                                      float* __restrict__ dq) {
    const int row  = blockIdx.x;       // g*256 + i
    const int lane = threadIdx.x;
    float4 v = *(const float4*)(Wh + (size_t)row * 256 + lane * 4);
    float m = fmaxf(fmaxf(fabsf(v.x), fabsf(v.y)), fmaxf(fabsf(v.z), fabsf(v.w)));
#pragma unroll
    for (int off = 32; off; off >>= 1) m = fmaxf(m, __shfl_xor(m, off));
    m = fmaxf(m, 1e-20f);
    float s = 127.f / m;
    int q0 = (int)rintf(v.x * s), q1 = (int)rintf(v.y * s);
    int q2 = (int)rintf(v.z * s), q3 = (int)rintf(v.w * s);
    unsigned int pk = (unsigned)(q0 & 255) | ((unsigned)(q1 & 255) << 8) |
                      ((unsigned)(q2 & 255) << 16) | ((unsigned)(q3 & 255) << 24);
    ((unsigned int*)Wq)[row * 64 + lane] = pk;          // k ascending from LSB
    if (lane == 0) dq[row] = m / 16129.f;               // maxw / 127^2
}

__global__ void __launch_bounds__(THREADS, 2) lstm_kernel(
    const float* __restrict__ x,     // [B, T]
    const float* __restrict__ Wx,    // [4*H]
    const float* __restrict__ bx,    // [4*H]
    const float* __restrict__ bh,    // [4*H]
    const char*  __restrict__ Wq,    // [4*H][H] i8
    const float* __restrict__ dq,    // [4*H] dequant scales
    const float* __restrict__ W_ph,  // [O, H]
    const float* __restrict__ b_ph,  // [O]
    float* __restrict__ out)         // [B, O]
{
    __shared__ __align__(16) char  h_q[2][16 * 256];    // i8 h, XOR-swizzled, dbuf (4KB each)
    __shared__ __align__(16) float x_sh[16 * XSTRIDE];  // x tile; fp32 h_T at the end

    const int tid   = threadIdx.x;
    const int wave  = tid >> 6;
    const int lane  = tid & 63;
    const int n     = lane & 15;    // A-frag row / B,C col within 16-tile
    const int grp   = lane >> 4;    // k-group (A/B) and row-group (C/D)
    const int b0    = blockIdx.x * BTILE;
    const int wcol0 = wave * 32;    // wave's first hidden column

    // ---- one-time staging ----
#pragma unroll
    for (int i = 0; i < 8; ++i) {
        int d = tid + i * 512;               // 4096 fp32
        int row = d >> 8, col = d & 255;
        x_sh[row * XSTRIDE + col] = x[(size_t)(b0 + row) * 256 + col];
    }
    ((ull*)h_q[0])[tid] = 0ull;              // zero h buffer 0 (4KB)

    // weight slice -> registers: 2 tiles x 4 gates x 4 ksteps x 16B = 128 VGPRs, pinned
    i32x4 bW[2][4][4];
#pragma unroll
    for (int tl = 0; tl < 2; ++tl)
#pragma unroll
        for (int g = 0; g < 4; ++g)
#pragma unroll
            for (int ks = 0; ks < 4; ++ks) {
                int col = wcol0 + tl * 16 + n;
                bW[tl][g][ks] = *(const i32x4*)(Wq + (size_t)(g * 256 + col) * 256
                                                + ks * 64 + grp * 16);
                asm volatile("" : "+v"(bW[tl][g][ks]));
            }

    float wxv[2][4], biv[2][4], dqv[2][4];
#pragma unroll
    for (int tl = 0; tl < 2; ++tl)
#pragma unroll
        for (int g = 0; g < 4; ++g) {
            int col = wcol0 + tl * 16 + n;
            wxv[tl][g] = Wx[g * 256 + col];
            biv[tl][g] = bx[g * 256 + col] + bh[g * 256 + col];
            dqv[tl][g] = dq[g * 256 + col];
        }

    float c_st[2][4] = {{0.f, 0.f, 0.f, 0.f}, {0.f, 0.f, 0.f, 0.f}};
    float hval[2][4];
    __syncthreads();

    for (int t = 0; t < LSTM_T; ++t) {
        const char* hb = h_q[t & 1];

        // A-frags: lane holds hq[row n][k = ks*64 + grp*16 .. +15]
        i32x4 aF[4];
#pragma unroll
        for (int ks = 0; ks < 4; ++ks) {
            int addr = (n * 256 + ks * 64 + grp * 16) ^ ((n & 7) << 4);
            aF[ks] = *(const i32x4*)(hb + addr);
        }

        i32x4 acc[2][4];
#pragma unroll
        for (int tl = 0; tl < 2; ++tl)
#pragma unroll
            for (int g = 0; g < 4; ++g) acc[tl][g] = (i32x4){0, 0, 0, 0};
#pragma unroll
        for (int tl = 0; tl < 2; ++tl)
#pragma unroll
            for (int g = 0; g < 4; ++g)
#pragma unroll
                for (int ks = 0; ks < 4; ++ks)
                    acc[tl][g] = __builtin_amdgcn_mfma_i32_16x16x64_i8(
                        aF[ks], bW[tl][g][ks], acc[tl][g], 0, 0, 0);

        // pointwise: lane owns rows r = grp*4+q, cols wcol0 + tl*16 + n
#pragma unroll
        for (int q = 0; q < 4; ++q) {
            int r = grp * 4 + q;
            float xt = x_sh[r * XSTRIDE + t];
#pragma unroll
            for (int tl = 0; tl < 2; ++tl) {
                float z0 = (float)acc[tl][0][q] * dqv[tl][0] + xt * wxv[tl][0] + biv[tl][0];
                float z1 = (float)acc[tl][1][q] * dqv[tl][1] + xt * wxv[tl][1] + biv[tl][1];
                float z2 = (float)acc[tl][2][q] * dqv[tl][2] + xt * wxv[tl][2] + biv[tl][2];
                float z3 = (float)acc[tl][3][q] * dqv[tl][3] + xt * wxv[tl][3] + biv[tl][3];
                float gg = tanh_f(z0);
                float ii = sigmoid_f(z1);
                float ff = sigmoid_f(z2);
                float oo = sigmoid_f(z3);
                float cn = gg * ii + c_st[tl][q] * ff;
                c_st[tl][q] = cn;
                hval[tl][q] = tanh_f(cn) * oo;
            }
        }

        if (t < LSTM_T - 1) {
            char* hbn = h_q[(t + 1) & 1];
#pragma unroll
            for (int q = 0; q < 4; ++q) {
                int r = grp * 4 + q;
#pragma unroll
                for (int tl = 0; tl < 2; ++tl) {
                    int col = wcol0 + tl * 16 + n;
                    int hq8 = (int)rintf(hval[tl][q] * 127.f);
                    hbn[(r * 256 + col) ^ ((r & 7) << 4)] = (char)hq8;
                }
            }
            LDS_BARRIER();   // h_{t+1} writes visible before next step's A reads
        } else {
            LDS_BARRIER();   // all x_sh reads of step 255 done before overwrite
#pragma unroll
            for (int q = 0; q < 4; ++q)
#pragma unroll
                for (int tl = 0; tl < 2; ++tl)
                    x_sh[(grp * 4 + q) * XSTRIDE + (wcol0 + tl * 16 + n)] = hval[tl][q];
            LDS_BARRIER();
        }
    }

    // fused output projection: out[b0+r][o] = h_T[r] . W_ph[o] + b_ph[o]
    if (tid < 16 * LSTM_O) {
        int r = tid & 15;
        int o = tid >> 4;
        const float* wrow = W_ph + o * 256;
        const float* hrow = x_sh + r * XSTRIDE;
        float s = 0.f;
#pragma unroll 4
        for (int k0 = 0; k0 < 256; ++k0) {
            int k = (k0 + r * 16) & 255;
            s += hrow[k] * wrow[k];
        }
        out[(size_t)(b0 + r) * LSTM_O + o] = s + b_ph[o];
    }
}

extern "C" void kernel_launch(void* const* d_in, const int* in_sizes, int n_in,
                              void* d_out, int out_size, void* d_ws, size_t ws_size,
                              hipStream_t stream) {
    const float* x    = (const float*)d_in[0];
    const float* Wx   = (const float*)d_in[1];
    const float* bx   = (const float*)d_in[2];
    const float* Wh   = (const float*)d_in[3];
    const float* bh   = (const float*)d_in[4];
    const float* W_ph = (const float*)d_in[5];
    const float* b_ph = (const float*)d_in[6];
    float* out = (float*)d_out;
    char* ws   = (char*)d_ws;

    quant_wh_kernel<<<1024, 64, 0, stream>>>(Wh, ws + WS_WQ, (float*)(ws + WS_DQ));
    lstm_kernel<<<NBLK, THREADS, 0, stream>>>(x, Wx, bx, bh, ws + WS_WQ,
                                              (const float*)(ws + WS_DQ), W_ph, b_ph, out);
}

// Round 9
// 376.489 us; speedup vs baseline: 24.7215x; 2.5125x over previous
//
#include <hip/hip_runtime.h>
#include <hip/hip_bf16.h>

typedef int  i32x4 __attribute__((ext_vector_type(4)));
typedef unsigned long long ull;

#define LSTM_T 256
#define LSTM_O 10
#define BTILE 8
#define NBLK 256     // 2048/8 batch tiles -> one block per CU
#define THREADS 512  // 8 waves; wave w owns hidden cols [w*32, w*32+32)
#define XSTRIDE 260

// ws: [0, 256KB) i8 weights Wq[4*256][256]; [256KB, +4KB) fp32 dequant dq[1024]
#define WS_WQ 0
#define WS_DQ (256 * 1024)

// fast activations: v_exp_f32 + v_rcp_f32 (1-ULP rcp, fine vs 1e-3 tolerance).
// Saturation-safe: exp->inf gives rcp(inf)=0; exp->0 gives rcp(1)=1.
__device__ __forceinline__ float sigmoid_f(float x) {
    return __builtin_amdgcn_rcpf(1.0f + __expf(-x));
}
__device__ __forceinline__ float tanh_f(float x) {
    return fmaf(2.0f, __builtin_amdgcn_rcpf(1.0f + __expf(-2.0f * x)), -1.0f);
}

// one barrier per step; only LDS traffic inside the loop
#define LDS_BARRIER() asm volatile("s_waitcnt lgkmcnt(0)\n\ts_barrier" ::: "memory")

// per-(gate,out-col) symmetric i8 quantization of Wh; one wave per row
__global__ void __launch_bounds__(64) quant_wh_kernel(const float* __restrict__ Wh,
                                                      char* __restrict__ Wq,
                                                      float* __restrict__ dq) {
    const int row  = blockIdx.x;       // g*256 + i
    const int lane = threadIdx.x;
    float4 v = *(const float4*)(Wh + (size_t)row * 256 + lane * 4);
    float m = fmaxf(fmaxf(fabsf(v.x), fabsf(v.y)), fmaxf(fabsf(v.z), fabsf(v.w)));
#pragma unroll
    for (int off = 32; off; off >>= 1) m = fmaxf(m, __shfl_xor(m, off));
    m = fmaxf(m, 1e-20f);
    float s = 127.f / m;
    int q0 = (int)rintf(v.x * s), q1 = (int)rintf(v.y * s);
    int q2 = (int)rintf(v.z * s), q3 = (int)rintf(v.w * s);
    unsigned int pk = (unsigned)(q0 & 255) | ((unsigned)(q1 & 255) << 8) |
                      ((unsigned)(q2 & 255) << 16) | ((unsigned)(q3 & 255) << 24);
    ((unsigned int*)Wq)[row * 64 + lane] = pk;          // k ascending from LSB
    if (lane == 0) dq[row] = m / 16129.f;               // maxw / 127^2
}

__global__ void __launch_bounds__(THREADS, 2) lstm_kernel(
    const float* __restrict__ x,     // [B, T]
    const float* __restrict__ Wx,    // [4*H]
    const float* __restrict__ bx,    // [4*H]
    const float* __restrict__ bh,    // [4*H]
    const char*  __restrict__ Wq,    // [4*H][H] i8
    const float* __restrict__ dq,    // [4*H] dequant scales
    const float* __restrict__ W_ph,  // [O, H]
    const float* __restrict__ b_ph,  // [O]
    float* __restrict__ out)         // [B, O]
{
    __shared__ __align__(16) char  h_q[2][8 * 256];     // i8 h, ^(r<<5) swizzle, dbuf (2KB each)
    __shared__ __align__(16) float x_sh[8 * XSTRIDE];   // x tile; fp32 h_T at the end

    const int tid   = threadIdx.x;
    const int wave  = tid >> 6;
    const int lane  = tid & 63;
    const int n     = lane & 15;       // B col within 16-tile / A row (mod 8 dup)
    const int grp   = lane >> 4;       // 0..3
    const int b0    = blockIdx.x * BTILE;
    const int wcol0 = wave * 32;
    const int tlo   = grp >> 1;        // which 16-col subtile this lane's OUTPUTS are in
    const int rbase = (grp & 1) * 4;   // output row base (rows rbase..rbase+3)
    const int mycol = wcol0 + tlo * 16 + n;   // this lane's output hidden column

    // ---- one-time staging ----
#pragma unroll
    for (int i = 0; i < 4; ++i) {
        int d = tid + i * 512;               // 2048 fp32 of x tile [8][256]
        int row = d >> 8, col = d & 255;
        x_sh[row * XSTRIDE + col] = x[(size_t)(b0 + row) * 256 + col];
    }
    if (tid < 256) ((ull*)h_q[0])[tid] = 0ull;   // zero h buffer 0 (2KB)

    // weight slice -> registers: 2 subtiles x 4 gates x 4 ksteps x 16B = 128 VGPRs, pinned
    i32x4 bW[2][4][4];
#pragma unroll
    for (int tl = 0; tl < 2; ++tl)
#pragma unroll
        for (int g = 0; g < 4; ++g)
#pragma unroll
            for (int ks = 0; ks < 4; ++ks) {
                int col = wcol0 + tl * 16 + n;
                bW[tl][g][ks] = *(const i32x4*)(Wq + (size_t)(g * 256 + col) * 256
                                                + ks * 64 + grp * 16);
                asm volatile("" : "+v"(bW[tl][g][ks]));
            }

    float wxv[4], biv[4], dqv[4];
#pragma unroll
    for (int g = 0; g < 4; ++g) {
        wxv[g] = Wx[g * 256 + mycol];
        biv[g] = bx[g * 256 + mycol] + bh[g * 256 + mycol];
        dqv[g] = dq[g * 256 + mycol];
    }

    float c_st[4] = {0.f, 0.f, 0.f, 0.f};
    float hval[4];
    __syncthreads();

    for (int t = 0; t < LSTM_T; ++t) {
        const char* hb = h_q[t & 1];

        // A-frags with duplicated rows: A[m] = h[m&7]  (lanes n and n+8 broadcast-read)
        i32x4 aF[4];
#pragma unroll
        for (int ks = 0; ks < 4; ++ks) {
            int r8   = n & 7;
            int addr = ((r8 * 256 + ks * 64 + grp * 16)) ^ (r8 << 5);
            aF[ks] = *(const i32x4*)(hb + addr);
        }

        i32x4 acc[2][4];
#pragma unroll
        for (int tl = 0; tl < 2; ++tl)
#pragma unroll
            for (int g = 0; g < 4; ++g) acc[tl][g] = (i32x4){0, 0, 0, 0};
#pragma unroll
        for (int tl = 0; tl < 2; ++tl)
#pragma unroll
            for (int g = 0; g < 4; ++g)
#pragma unroll
                for (int ks = 0; ks < 4; ++ks)
                    acc[tl][g] = __builtin_amdgcn_mfma_i32_16x16x64_i8(
                        aF[ks], bW[tl][g][ks], acc[tl][g], 0, 0, 0);

        // pointwise: lane owns 4 outputs — rows rbase+q, col mycol, from subtile tlo.
        // static-index both subtiles + cndmask select (rule #20: no runtime array index)
#pragma unroll
        for (int q = 0; q < 4; ++q) {
            int r = rbase + q;
            float xt = x_sh[r * XSTRIDE + t];
            float a0 = (float)(tlo ? acc[1][0][q] : acc[0][0][q]);
            float a1 = (float)(tlo ? acc[1][1][q] : acc[0][1][q]);
            float a2 = (float)(tlo ? acc[1][2][q] : acc[0][2][q]);
            float a3 = (float)(tlo ? acc[1][3][q] : acc[0][3][q]);
            float z0 = fmaf(a0, dqv[0], fmaf(xt, wxv[0], biv[0]));
            float z1 = fmaf(a1, dqv[1], fmaf(xt, wxv[1], biv[1]));
            float z2 = fmaf(a2, dqv[2], fmaf(xt, wxv[2], biv[2]));
            float z3 = fmaf(a3, dqv[3], fmaf(xt, wxv[3], biv[3]));
            float gg = tanh_f(z0);
            float ii = sigmoid_f(z1);
            float ff = sigmoid_f(z2);
            float oo = sigmoid_f(z3);
            float cn = fmaf(gg, ii, c_st[q] * ff);
            c_st[q] = cn;
            hval[q] = tanh_f(cn) * oo;
        }

        if (t < LSTM_T - 1) {
            char* hbn = h_q[(t + 1) & 1];
#pragma unroll
            for (int q = 0; q < 4; ++q) {
                int r = rbase + q;
                int hq8 = (int)rintf(hval[q] * 127.f);
                hbn[(r * 256 + mycol) ^ (r << 5)] = (char)hq8;
            }
            LDS_BARRIER();   // h_{t+1} writes visible before next step's A reads
        } else {
            LDS_BARRIER();   // all x_sh reads of step 255 done before overwrite
#pragma unroll
            for (int q = 0; q < 4; ++q)
                x_sh[(rbase + q) * XSTRIDE + mycol] = hval[q];   // fp32 h_T
            LDS_BARRIER();
        }
    }

    // fused output projection: out[b0+r][o] = h_T[r] . W_ph[o] + b_ph[o]
    if (tid < 8 * LSTM_O) {
        int r = tid & 7;
        int o = tid >> 3;
        const float* wrow = W_ph + o * 256;
        const float* hrow = x_sh + r * XSTRIDE;
        float s = 0.f;
#pragma unroll 4
        for (int k0 = 0; k0 < 256; ++k0) {
            int k = (k0 + r * 32) & 255;   // rotate start vs LDS bank conflicts
            s += hrow[k] * wrow[k];
        }
        out[(size_t)(b0 + r) * LSTM_O + o] = s + b_ph[o];
    }
}

extern "C" void kernel_launch(void* const* d_in, const int* in_sizes, int n_in,
                              void* d_out, int out_size, void* d_ws, size_t ws_size,
                              hipStream_t stream) {
    const float* x    = (const float*)d_in[0];
    const float* Wx   = (const float*)d_in[1];
    const float* bx   = (const float*)d_in[2];
    const float* Wh   = (const float*)d_in[3];
    const float* bh   = (const float*)d_in[4];
    const float* W_ph = (const float*)d_in[5];
    const float* b_ph = (const float*)d_in[6];
    float* out = (float*)d_out;
    char* ws   = (char*)d_ws;

    quant_wh_kernel<<<1024, 64, 0, stream>>>(Wh, ws + WS_WQ, (float*)(ws + WS_DQ));
    lstm_kernel<<<NBLK, THREADS, 0, stream>>>(x, Wx, bx, bh, ws + WS_WQ,
                                              (const float*)(ws + WS_DQ), W_ph, b_ph, out);
}

// Round 10
// 368.617 us; speedup vs baseline: 25.2494x; 1.0214x over previous
//
#include <hip/hip_runtime.h>
#include <hip/hip_bf16.h>

typedef int  i32x4 __attribute__((ext_vector_type(4)));
typedef unsigned long long ull;

#define LSTM_T 256
#define LSTM_O 10
#define BTILE 8
#define NBLK 256      // 2048/8 batch tiles -> one block per CU
#define THREADS 1024  // 16 waves; wave w owns hidden cols [w*16, w*16+16)
#define XSTRIDE 260

// ws: [0, 256KB) i8 weights Wq[4*256][256]; [256KB, +4KB) fp32 dequant dq[1024]
#define WS_WQ 0
#define WS_DQ (256 * 1024)

// fast activations: v_exp_f32 + v_rcp_f32 (1-ULP rcp, fine vs 1e-3 tolerance).
// Saturation-safe: exp->inf gives rcp(inf)=0; exp->0 gives rcp(1)=1.
__device__ __forceinline__ float sigmoid_f(float x) {
    return __builtin_amdgcn_rcpf(1.0f + __expf(-x));
}
__device__ __forceinline__ float tanh_f(float x) {
    return fmaf(2.0f, __builtin_amdgcn_rcpf(1.0f + __expf(-2.0f * x)), -1.0f);
}

// one barrier per step; only LDS traffic inside the loop
#define LDS_BARRIER() asm volatile("s_waitcnt lgkmcnt(0)\n\ts_barrier" ::: "memory")

// per-(gate,out-col) symmetric i8 quantization of Wh; one wave per row
__global__ void __launch_bounds__(64) quant_wh_kernel(const float* __restrict__ Wh,
                                                      char* __restrict__ Wq,
                                                      float* __restrict__ dq) {
    const int row  = blockIdx.x;       // g*256 + i
    const int lane = threadIdx.x;
    float4 v = *(const float4*)(Wh + (size_t)row * 256 + lane * 4);
    float m = fmaxf(fmaxf(fabsf(v.x), fabsf(v.y)), fmaxf(fabsf(v.z), fabsf(v.w)));
#pragma unroll
    for (int off = 32; off; off >>= 1) m = fmaxf(m, __shfl_xor(m, off));
    m = fmaxf(m, 1e-20f);
    float s = 127.f / m;
    int q0 = (int)rintf(v.x * s), q1 = (int)rintf(v.y * s);
    int q2 = (int)rintf(v.z * s), q3 = (int)rintf(v.w * s);
    unsigned int pk = (unsigned)(q0 & 255) | ((unsigned)(q1 & 255) << 8) |
                      ((unsigned)(q2 & 255) << 16) | ((unsigned)(q3 & 255) << 24);
    ((unsigned int*)Wq)[row * 64 + lane] = pk;          // k ascending from LSB
    if (lane == 0) dq[row] = m / 16129.f;               // maxw / 127^2
}

__global__ void __launch_bounds__(THREADS, 4) lstm_kernel(
    const float* __restrict__ x,     // [B, T]
    const float* __restrict__ Wx,    // [4*H]
    const float* __restrict__ bx,    // [4*H]
    const float* __restrict__ bh,    // [4*H]
    const char*  __restrict__ Wq,    // [4*H][H] i8
    const float* __restrict__ dq,    // [4*H] dequant scales
    const float* __restrict__ W_ph,  // [O, H]
    const float* __restrict__ b_ph,  // [O]
    float* __restrict__ out)         // [B, O]
{
    __shared__ __align__(16) char  h_q[2][8 * 256];     // i8 h, ^(r<<5) swizzle, dbuf (2KB each)
    __shared__ __align__(16) float x_sh[8 * XSTRIDE];   // x tile; fp32 h_T at the end

    const int tid   = threadIdx.x;
    const int wave  = tid >> 6;
    const int lane  = tid & 63;
    const int n     = lane & 15;       // B col within 16-tile / A row (mod 8 dup)
    const int grp   = lane >> 4;       // 0..3
    const int b0    = blockIdx.x * BTILE;
    const int hi    = grp >> 1;        // which q-pair of the acc this lane extracts
    const int rbase = (grp & 1) * 4 + hi * 2;   // output rows rbase, rbase+1
    const int mycol = wave * 16 + n;   // this lane's output hidden column

    // ---- one-time staging ----
#pragma unroll
    for (int i = 0; i < 2; ++i) {
        int d = tid + i * 1024;              // 2048 fp32 of x tile [8][256]
        int row = d >> 8, col = d & 255;
        x_sh[row * XSTRIDE + col] = x[(size_t)(b0 + row) * 256 + col];
    }
    if (tid < 256) ((ull*)h_q[0])[tid] = 0ull;   // zero h buffer 0 (2KB)

    // weight subtile -> registers: 4 gates x 4 ksteps x 16B = 64 VGPRs, pinned
    i32x4 bW[4][4];
#pragma unroll
    for (int g = 0; g < 4; ++g)
#pragma unroll
        for (int ks = 0; ks < 4; ++ks) {
            bW[g][ks] = *(const i32x4*)(Wq + (size_t)(g * 256 + mycol) * 256
                                        + ks * 64 + grp * 16);
            asm volatile("" : "+v"(bW[g][ks]));
        }

    float wxv[4], biv[4], dqv[4];
#pragma unroll
    for (int g = 0; g < 4; ++g) {
        wxv[g] = Wx[g * 256 + mycol];
        biv[g] = bx[g * 256 + mycol] + bh[g * 256 + mycol];
        dqv[g] = dq[g * 256 + mycol];
    }

    float c_st[2] = {0.f, 0.f};
    float hval[2];
    __syncthreads();

    for (int t = 0; t < LSTM_T; ++t) {
        const char* hb = h_q[t & 1];

        // A-frags with duplicated rows: A[m] = h[m&7]
        i32x4 aF[4];
#pragma unroll
        for (int ks = 0; ks < 4; ++ks) {
            int r8   = n & 7;
            int addr = (r8 * 256 + ks * 64 + grp * 16) ^ (r8 << 5);
            aF[ks] = *(const i32x4*)(hb + addr);
        }

        i32x4 acc[4];
#pragma unroll
        for (int g = 0; g < 4; ++g) acc[g] = (i32x4){0, 0, 0, 0};
#pragma unroll
        for (int g = 0; g < 4; ++g)
#pragma unroll
            for (int ks = 0; ks < 4; ++ks)
                acc[g] = __builtin_amdgcn_mfma_i32_16x16x64_i8(
                    aF[ks], bW[g][ks], acc[g], 0, 0, 0);

        // pointwise: lane owns 2 outputs — rows rbase+qq, col mycol.
        // acc row (grp*4+q)&7 duplicates across (grp0,grp2) and (grp1,grp3);
        // hi selects which q-pair is this lane's (1 cndmask per element, static idx)
#pragma unroll
        for (int qq = 0; qq < 2; ++qq) {
            int r = rbase + qq;
            float xt = x_sh[r * XSTRIDE + t];
            int a0i = hi ? acc[0][qq + 2] : acc[0][qq];
            int a1i = hi ? acc[1][qq + 2] : acc[1][qq];
            int a2i = hi ? acc[2][qq + 2] : acc[2][qq];
            int a3i = hi ? acc[3][qq + 2] : acc[3][qq];
            float z0 = fmaf((float)a0i, dqv[0], fmaf(xt, wxv[0], biv[0]));
            float z1 = fmaf((float)a1i, dqv[1], fmaf(xt, wxv[1], biv[1]));
            float z2 = fmaf((float)a2i, dqv[2], fmaf(xt, wxv[2], biv[2]));
            float z3 = fmaf((float)a3i, dqv[3], fmaf(xt, wxv[3], biv[3]));
            float gg = tanh_f(z0);
            float ii = sigmoid_f(z1);
            float ff = sigmoid_f(z2);
            float oo = sigmoid_f(z3);
            float cn = fmaf(gg, ii, c_st[qq] * ff);
            c_st[qq] = cn;
            hval[qq] = tanh_f(cn) * oo;
        }

        if (t < LSTM_T - 1) {
            char* hbn = h_q[(t + 1) & 1];
#pragma unroll
            for (int qq = 0; qq < 2; ++qq) {
                int r = rbase + qq;
                int hq8 = (int)rintf(hval[qq] * 127.f);
                hbn[(r * 256 + mycol) ^ (r << 5)] = (char)hq8;
            }
            LDS_BARRIER();   // h_{t+1} writes visible before next step's A reads
        } else {
            LDS_BARRIER();   // all x_sh reads of step 255 done before overwrite
#pragma unroll
            for (int qq = 0; qq < 2; ++qq)
                x_sh[(rbase + qq) * XSTRIDE + mycol] = hval[qq];   // fp32 h_T
            LDS_BARRIER();
        }
    }

    // fused output projection: out[b0+r][o] = h_T[r] . W_ph[o] + b_ph[o]
    if (tid < 8 * LSTM_O) {
        int r = tid & 7;
        int o = tid >> 3;
        const float* wrow = W_ph + o * 256;
        const float* hrow = x_sh + r * XSTRIDE;
        float s = 0.f;
#pragma unroll 4
        for (int k0 = 0; k0 < 256; ++k0) {
            int k = (k0 + r * 32) & 255;   // rotate start vs LDS bank conflicts
            s += hrow[k] * wrow[k];
        }
        out[(size_t)(b0 + r) * LSTM_O + o] = s + b_ph[o];
    }
}

extern "C" void kernel_launch(void* const* d_in, const int* in_sizes, int n_in,
                              void* d_out, int out_size, void* d_ws, size_t ws_size,
                              hipStream_t stream) {
    const float* x    = (const float*)d_in[0];
    const float* Wx   = (const float*)d_in[1];
    const float* bx   = (const float*)d_in[2];
    const float* Wh   = (const float*)d_in[3];
    const float* bh   = (const float*)d_in[4];
    const float* W_ph = (const float*)d_in[5];
    const float* b_ph = (const float*)d_in[6];
    float* out = (float*)d_out;
    char* ws   = (char*)d_ws;

    quant_wh_kernel<<<1024, 64, 0, stream>>>(Wh, ws + WS_WQ, (float*)(ws + WS_DQ));
    lstm_kernel<<<NBLK, THREADS, 0, stream>>>(x, Wx, bx, bh, ws + WS_WQ,
                                              (const float*)(ws + WS_DQ), W_ph, b_ph, out);
}